// Round 1
// baseline (615.638 us; speedup 1.0000x reference)
//
#include <hip/hip_runtime.h>
#include <cstdint>
#include <cstddef>

typedef __bf16 bf16;
typedef __attribute__((ext_vector_type(8))) __bf16 bf16x8;
typedef __attribute__((ext_vector_type(4))) __bf16 bf16x4;
typedef __attribute__((ext_vector_type(4))) float f32x4;

#define MFMA_16x16x32(a, b, c) __builtin_amdgcn_mfma_f32_16x16x32_bf16((a), (b), (c), 0, 0, 0)

__device__ __forceinline__ void gload_lds16(const void* g, void* l) {
  __builtin_amdgcn_global_load_lds((__attribute__((address_space(1))) void*)g,
                                   (__attribute__((address_space(3))) void*)l,
                                   16, 0, 0);
}

// ---------------------------------------------------------------------------
// fp32 -> bf16 convert (grid covers exactly n/4 elements, n = 4096*1024)
// ---------------------------------------------------------------------------
__global__ __launch_bounds__(256) void cvt_x_kernel(const float* __restrict__ in,
                                                    bf16* __restrict__ out) {
  int i = blockIdx.x * 256 + threadIdx.x;
  float4 v = ((const float4*)in)[i];
  bf16x4 o = {(bf16)v.x, (bf16)v.y, (bf16)v.z, (bf16)v.w};
  ((bf16x4*)out)[i] = o;
}

// ---------------------------------------------------------------------------
// transpose + convert: in fp32 [R][C] -> out bf16 [C][R]
// ---------------------------------------------------------------------------
__global__ __launch_bounds__(256) void transpose_cvt_kernel(const float* __restrict__ in,
                                                            bf16* __restrict__ out,
                                                            int R, int C) {
  __shared__ float tile[32][33];
  int tiles_c = C >> 5;
  int br = (int)blockIdx.x / tiles_c, bc = (int)blockIdx.x % tiles_c;
  int r0 = br << 5, c0 = bc << 5;
  int tr = threadIdx.x >> 5, tc = threadIdx.x & 31;
#pragma unroll
  for (int i = 0; i < 4; i++)
    tile[tr + 8 * i][tc] = in[(size_t)(r0 + tr + 8 * i) * C + c0 + tc];
  __syncthreads();
#pragma unroll
  for (int i = 0; i < 4; i++) {
    int oc = tr + 8 * i;
    out[(size_t)(c0 + oc) * R + r0 + tc] = (bf16)tile[tc][oc];
  }
}

// ---------------------------------------------------------------------------
// bf16 GEMM: C[m][n] = sum_k A[m][k] * Bt[n][k] + bias[n]
// 128x128 tile, BK=64, 4 waves (2x2), mfma_f32_16x16x32_bf16, global_load_lds.
// EPI 0: bf16 out [M][N].  EPI 1: bf16 out transposed per head ->
//        Vt[b][h][192][2048] (N==3072, token rows).  EPI 2: fp32 out [M][N].
// ---------------------------------------------------------------------------
template <int EPI>
__global__ __launch_bounds__(256, 2) void gemm_bf16_kernel(const bf16* __restrict__ A,
                                                           const bf16* __restrict__ Bt,
                                                           const float* __restrict__ bias,
                                                           void* __restrict__ Cout,
                                                           int M, int N, int K) {
  __shared__ __align__(16) bf16 sA[128 * 64];
  __shared__ __align__(16) bf16 sB[128 * 64];
  int tiles_n = N >> 7;
  int bm = (int)blockIdx.x / tiles_n, bn = (int)blockIdx.x % tiles_n;
  int m0 = bm << 7, n0 = bn << 7;
  int tid = threadIdx.x, lane = tid & 63, w = tid >> 6;
  int wr = w >> 1, wc = w & 1;
  int l15 = lane & 15, lg = lane >> 4;
  int sr = lane >> 3, sc = lane & 7;  // staging: 8 lanes per 64-elem row

  f32x4 acc[4][4];
#pragma unroll
  for (int mf = 0; mf < 4; mf++)
#pragma unroll
    for (int nf = 0; nf < 4; nf++) acc[mf][nf] = (f32x4){0.f, 0.f, 0.f, 0.f};

  int nkt = K >> 6;
  for (int kt = 0; kt < nkt; kt++) {
    __syncthreads();
#pragma unroll
    for (int i = 0; i < 4; i++) {
      int iw = w * 4 + i;           // wave-uniform
      int row = iw * 8 + sr;        // per-lane
      gload_lds16(A + (size_t)(m0 + row) * K + kt * 64 + sc * 8, &sA[iw * 512]);
      gload_lds16(Bt + (size_t)(n0 + row) * K + kt * 64 + sc * 8, &sB[iw * 512]);
    }
    __syncthreads();
#pragma unroll
    for (int ks = 0; ks < 2; ks++) {
      bf16x8 af[4], bfr[4];
#pragma unroll
      for (int mf = 0; mf < 4; mf++)
        af[mf] = *(const bf16x8*)&sA[(wr * 64 + mf * 16 + l15) * 64 + ks * 32 + lg * 8];
#pragma unroll
      for (int nf = 0; nf < 4; nf++)
        bfr[nf] = *(const bf16x8*)&sB[(wc * 64 + nf * 16 + l15) * 64 + ks * 32 + lg * 8];
#pragma unroll
      for (int mf = 0; mf < 4; mf++)
#pragma unroll
        for (int nf = 0; nf < 4; nf++)
          acc[mf][nf] = MFMA_16x16x32(af[mf], bfr[nf], acc[mf][nf]);
    }
  }

#pragma unroll
  for (int mf = 0; mf < 4; mf++) {
#pragma unroll
    for (int nf = 0; nf < 4; nf++) {
      int col = n0 + wc * 64 + nf * 16 + l15;
      int row0 = m0 + wr * 64 + mf * 16 + lg * 4;
      float biasv = bias[col];
      if (EPI == 0) {
        bf16* out = (bf16*)Cout;
#pragma unroll
        for (int r = 0; r < 4; r++)
          out[(size_t)(row0 + r) * N + col] = (bf16)(acc[mf][nf][r] + biasv);
      } else if (EPI == 1) {
        // col -> (h, d); token row0..row0+3 -> (b, n..n+3) contiguous
        bf16* out = (bf16*)Cout;
        int hh = col / 192, dd = col % 192;
        int bi = row0 >> 11, nn = row0 & 2047;
        bf16x4 pk = {(bf16)(acc[mf][nf][0] + biasv), (bf16)(acc[mf][nf][1] + biasv),
                     (bf16)(acc[mf][nf][2] + biasv), (bf16)(acc[mf][nf][3] + biasv)};
        *(bf16x4*)(out + (((size_t)bi * 16 + hh) * 192 + dd) * 2048 + nn) = pk;
      } else {
        float* out = (float*)Cout;
#pragma unroll
        for (int r = 0; r < 4; r++)
          out[(size_t)(row0 + r) * N + col] = acc[mf][nf][r] + biasv;
      }
    }
  }
}

// ---------------------------------------------------------------------------
// Flash attention.  Q,K: [4096][3072] bf16 (head slice at h*192, row stride
// 3072).  Vt: [32][192][2048] bf16.  inter out: [4096][3072] bf16.
// Grid: 512 blocks = 32 (b,h) x 16 q-tiles of 128 rows.  4 waves x 32 q-rows.
// KBLK = 64 keys/iter.  scale = 1/32.
// ---------------------------------------------------------------------------
__global__ __launch_bounds__(256, 2) void attn_kernel(const bf16* __restrict__ Q,
                                                      const bf16* __restrict__ Km,
                                                      const bf16* __restrict__ Vt,
                                                      bf16* __restrict__ inter) {
  __shared__ __align__(16) bf16 sK[64][200];    // 64 keys x 192 d (+8 pad)
  __shared__ __align__(16) bf16 sV[192][72];    // 192 d x 64 keys (+8 pad)
  __shared__ __align__(16) bf16 sP[4][32][72];  // per-wave P tile

  int bid = blockIdx.x;
  int bh = bid >> 4, qt = bid & 15;
  int b = bh >> 4, h = bh & 15;
  int tid = threadIdx.x, lane = tid & 63, w = tid >> 6;
  int l15 = lane & 15, lg = lane >> 4;

  const bf16* Qh = Q + (size_t)b * 2048 * 3072 + (size_t)h * 192;
  const bf16* Kh = Km + (size_t)b * 2048 * 3072 + (size_t)h * 192;
  const bf16* Vh = Vt + (size_t)bh * 192 * 2048;

  int q0 = qt * 128 + w * 32;

  // Q fragments in registers for the whole kernel: 2 row-frags x 6 k-chunks
  bf16x8 aq[2][6];
#pragma unroll
  for (int rf = 0; rf < 2; rf++)
#pragma unroll
    for (int kc = 0; kc < 6; kc++)
      aq[rf][kc] = *(const bf16x8*)(Qh + (size_t)(q0 + rf * 16 + l15) * 3072 + kc * 32 + lg * 8);

  f32x4 o[2][12];
#pragma unroll
  for (int rf = 0; rf < 2; rf++)
#pragma unroll
    for (int cf = 0; cf < 12; cf++) o[rf][cf] = (f32x4){0.f, 0.f, 0.f, 0.f};
  float mrow[2][4], lrow[2][4];
#pragma unroll
  for (int rf = 0; rf < 2; rf++)
#pragma unroll
    for (int r = 0; r < 4; r++) {
      mrow[rf][r] = -1e30f;
      lrow[rf][r] = 0.f;
    }

  const float scale = 0.03125f;  // 1/sqrt(1024)

  for (int kt = 0; kt < 32; kt++) {
    // ---- stage K tile [64][192] and V tile [192][64] via regs (padded LDS)
    uint4 rk[6], rv[6];
#pragma unroll
    for (int i = 0; i < 6; i++) {
      int id = tid + 256 * i;
      rk[i] = *(const uint4*)(Kh + (size_t)(kt * 64 + id / 24) * 3072 + (id % 24) * 8);
      rv[i] = *(const uint4*)(Vh + (size_t)(id >> 3) * 2048 + kt * 64 + (id & 7) * 8);
    }
    __syncthreads();
#pragma unroll
    for (int i = 0; i < 6; i++) {
      int id = tid + 256 * i;
      *(uint4*)&sK[id / 24][(id % 24) * 8] = rk[i];
      *(uint4*)&sV[id >> 3][(id & 7) * 8] = rv[i];
    }
    __syncthreads();

    // ---- S = Q K^T  (per wave: 32 q rows x 64 keys)
    f32x4 s[2][4];
#pragma unroll
    for (int rf = 0; rf < 2; rf++)
#pragma unroll
      for (int kf = 0; kf < 4; kf++) s[rf][kf] = (f32x4){0.f, 0.f, 0.f, 0.f};
#pragma unroll
    for (int kc = 0; kc < 6; kc++) {
#pragma unroll
      for (int kf = 0; kf < 4; kf++) {
        bf16x8 bk = *(const bf16x8*)&sK[kf * 16 + l15][kc * 32 + lg * 8];
        s[0][kf] = MFMA_16x16x32(aq[0][kc], bk, s[0][kf]);
        s[1][kf] = MFMA_16x16x32(aq[1][kc], bk, s[1][kf]);
      }
    }

    // ---- online softmax (fp32)
#pragma unroll
    for (int rf = 0; rf < 2; rf++) {
#pragma unroll
      for (int r = 0; r < 4; r++) {
        float v0 = s[rf][0][r] * scale, v1 = s[rf][1][r] * scale;
        float v2 = s[rf][2][r] * scale, v3 = s[rf][3][r] * scale;
        float pm = fmaxf(fmaxf(v0, v1), fmaxf(v2, v3));
#pragma unroll
        for (int off = 1; off < 16; off <<= 1) pm = fmaxf(pm, __shfl_xor(pm, off));
        float mn = fmaxf(mrow[rf][r], pm);
        float corr = __expf(mrow[rf][r] - mn);
        mrow[rf][r] = mn;
        float p0 = __expf(v0 - mn), p1 = __expf(v1 - mn);
        float p2 = __expf(v2 - mn), p3 = __expf(v3 - mn);
        s[rf][0][r] = p0; s[rf][1][r] = p1; s[rf][2][r] = p2; s[rf][3][r] = p3;
        float rs = p0 + p1 + p2 + p3;
#pragma unroll
        for (int off = 1; off < 16; off <<= 1) rs += __shfl_xor(rs, off);
        lrow[rf][r] = lrow[rf][r] * corr + rs;
#pragma unroll
        for (int cf = 0; cf < 12; cf++) o[rf][cf][r] *= corr;
      }
    }

    // ---- P -> LDS (per-wave buffer, padded rows)
#pragma unroll
    for (int rf = 0; rf < 2; rf++)
#pragma unroll
      for (int kf = 0; kf < 4; kf++)
#pragma unroll
        for (int r = 0; r < 4; r++)
          sP[w][rf * 16 + lg * 4 + r][kf * 16 + l15] = (bf16)s[rf][kf][r];

    // ---- O += P V
#pragma unroll
    for (int ks = 0; ks < 2; ks++) {
      bf16x8 pa0 = *(const bf16x8*)&sP[w][l15][ks * 32 + lg * 8];
      bf16x8 pa1 = *(const bf16x8*)&sP[w][16 + l15][ks * 32 + lg * 8];
#pragma unroll
      for (int cf = 0; cf < 12; cf++) {
        bf16x8 bv = *(const bf16x8*)&sV[cf * 16 + l15][ks * 32 + lg * 8];
        o[0][cf] = MFMA_16x16x32(pa0, bv, o[0][cf]);
        o[1][cf] = MFMA_16x16x32(pa1, bv, o[1][cf]);
      }
    }
  }

  // ---- epilogue: normalize and write inter[token][h*192 + d]
#pragma unroll
  for (int rf = 0; rf < 2; rf++) {
    float inv[4];
#pragma unroll
    for (int r = 0; r < 4; r++) inv[r] = 1.0f / lrow[rf][r];
#pragma unroll
    for (int cf = 0; cf < 12; cf++)
#pragma unroll
      for (int r = 0; r < 4; r++) {
        size_t row = (size_t)b * 2048 + q0 + rf * 16 + lg * 4 + r;
        inter[row * 3072 + h * 192 + cf * 16 + l15] = (bf16)(o[rf][cf][r] * inv[r]);
      }
  }
}

// ---------------------------------------------------------------------------
extern "C" void kernel_launch(void* const* d_in, const int* in_sizes, int n_in,
                              void* d_out, int out_size, void* d_ws, size_t ws_size,
                              hipStream_t stream) {
  const float* X = (const float*)d_in[0];
  const float* q_w = (const float*)d_in[1];
  const float* q_b = (const float*)d_in[2];
  const float* k_w = (const float*)d_in[3];
  const float* k_b = (const float*)d_in[4];
  const float* v_w = (const float*)d_in[5];
  const float* v_b = (const float*)d_in[6];
  const float* o_w = (const float*)d_in[7];
  const float* o_b = (const float*)d_in[8];

  char* ws = (char*)d_ws;
  bf16* Xb  = (bf16*)(ws);                    //  8 MiB: X bf16 [4096][1024]
  bf16* Wqt = (bf16*)(ws + 8388608);          //  6 MiB: q_w^T [3072][1024]
  bf16* Wvt = (bf16*)(ws + 14680064);         //  6 MiB: v_w^T (-> k_mat)
  bf16* Wkt = (bf16*)(ws + 20971520);         //  6 MiB: k_w^T (-> v_mat)
  bf16* Wot = (bf16*)(ws + 27262976);         //  6 MiB: o_w^T [1024][3072]
  bf16* Qm  = (bf16*)(ws + 33554432);         // 24 MiB: Q [4096][3072]
  bf16* Km  = (bf16*)(ws + 58720256);         // 24 MiB: K-attn [4096][3072]
  bf16* Vtw = (bf16*)(ws + 83886080);         // 24 MiB: V-attn^T [32][192][2048]
  bf16* Im  = (bf16*)(ws + 109051904);        // 24 MiB: inter [4096][3072]

  cvt_x_kernel<<<4096, 256, 0, stream>>>(X, Xb);
  transpose_cvt_kernel<<<3072, 256, 0, stream>>>(q_w, Wqt, 1024, 3072);
  transpose_cvt_kernel<<<3072, 256, 0, stream>>>(v_w, Wvt, 1024, 3072);
  transpose_cvt_kernel<<<3072, 256, 0, stream>>>(k_w, Wkt, 1024, 3072);
  transpose_cvt_kernel<<<3072, 256, 0, stream>>>(o_w, Wot, 3072, 1024);

  // quirk: k_mat uses v_w/v_b, v_mat uses k_w/k_b
  gemm_bf16_kernel<0><<<768, 256, 0, stream>>>(Xb, Wqt, q_b, Qm, 4096, 3072, 1024);
  gemm_bf16_kernel<0><<<768, 256, 0, stream>>>(Xb, Wvt, v_b, Km, 4096, 3072, 1024);
  gemm_bf16_kernel<1><<<768, 256, 0, stream>>>(Xb, Wkt, k_b, Vtw, 4096, 3072, 1024);

  attn_kernel<<<512, 256, 0, stream>>>(Qm, Km, Vtw, Im);

  gemm_bf16_kernel<2><<<256, 256, 0, stream>>>(Im, Wot, o_b, d_out, 4096, 1024, 3072);
}

// Round 2
// 490.063 us; speedup vs baseline: 1.2562x; 1.2562x over previous
//
#include <hip/hip_runtime.h>
#include <cstdint>
#include <cstddef>

typedef __bf16 bf16;
typedef __attribute__((ext_vector_type(8))) __bf16 bf16x8;
typedef __attribute__((ext_vector_type(4))) __bf16 bf16x4;
typedef __attribute__((ext_vector_type(2))) __bf16 bf16x2;
typedef __attribute__((ext_vector_type(4))) float f32x4;

#define MFMA_16x16x32(a, b, c) __builtin_amdgcn_mfma_f32_16x16x32_bf16((a), (b), (c), 0, 0, 0)

__device__ __forceinline__ void gload_lds16(const void* g, void* l) {
  __builtin_amdgcn_global_load_lds((__attribute__((address_space(1))) void*)g,
                                   (__attribute__((address_space(3))) void*)l,
                                   16, 0, 0);
}

__device__ __forceinline__ uint32_t pack2(float a, float b) {
  bf16x2 h = {(bf16)a, (bf16)b};
  return __builtin_bit_cast(uint32_t, h);
}

// ---------------------------------------------------------------------------
// fp32 -> bf16 convert (grid covers exactly n/4 elements, n = 4096*1024)
// ---------------------------------------------------------------------------
__global__ __launch_bounds__(256) void cvt_x_kernel(const float* __restrict__ in,
                                                    bf16* __restrict__ out) {
  int i = blockIdx.x * 256 + threadIdx.x;
  float4 v = ((const float4*)in)[i];
  bf16x4 o = {(bf16)v.x, (bf16)v.y, (bf16)v.z, (bf16)v.w};
  ((bf16x4*)out)[i] = o;
}

// ---------------------------------------------------------------------------
// transpose + convert: in fp32 [R][C] -> out bf16 [C][R]
// ---------------------------------------------------------------------------
__global__ __launch_bounds__(256) void transpose_cvt_kernel(const float* __restrict__ in,
                                                            bf16* __restrict__ out,
                                                            int R, int C) {
  __shared__ float tile[32][33];
  int tiles_c = C >> 5;
  int br = (int)blockIdx.x / tiles_c, bc = (int)blockIdx.x % tiles_c;
  int r0 = br << 5, c0 = bc << 5;
  int tr = threadIdx.x >> 5, tc = threadIdx.x & 31;
#pragma unroll
  for (int i = 0; i < 4; i++)
    tile[tr + 8 * i][tc] = in[(size_t)(r0 + tr + 8 * i) * C + c0 + tc];
  __syncthreads();
#pragma unroll
  for (int i = 0; i < 4; i++) {
    int oc = tr + 8 * i;
    out[(size_t)(c0 + oc) * R + r0 + tc] = (bf16)tile[tc][oc];
  }
}

// ---------------------------------------------------------------------------
// bf16 GEMM: C[m][n] = sum_k A[m][k] * Bt[n][k] + bias[n]
// 128x128 tile, BK=64, 4 waves (2x2), mfma_f32_16x16x32_bf16, global_load_lds.
// EPI 0: bf16 out [M][N].  EPI 1: bf16 out transposed per head ->
//        Vt[b][h][192][2048] (N==3072, token rows).  EPI 2: fp32 out [M][N].
// ---------------------------------------------------------------------------
template <int EPI>
__global__ __launch_bounds__(256, 2) void gemm_bf16_kernel(const bf16* __restrict__ A,
                                                           const bf16* __restrict__ Bt,
                                                           const float* __restrict__ bias,
                                                           void* __restrict__ Cout,
                                                           int M, int N, int K) {
  __shared__ __align__(16) bf16 sA[128 * 64];
  __shared__ __align__(16) bf16 sB[128 * 64];
  int tiles_n = N >> 7;
  int bm = (int)blockIdx.x / tiles_n, bn = (int)blockIdx.x % tiles_n;
  int m0 = bm << 7, n0 = bn << 7;
  int tid = threadIdx.x, lane = tid & 63, w = tid >> 6;
  int wr = w >> 1, wc = w & 1;
  int l15 = lane & 15, lg = lane >> 4;
  int sr = lane >> 3, sc = lane & 7;  // staging: 8 lanes per 64-elem row

  f32x4 acc[4][4];
#pragma unroll
  for (int mf = 0; mf < 4; mf++)
#pragma unroll
    for (int nf = 0; nf < 4; nf++) acc[mf][nf] = (f32x4){0.f, 0.f, 0.f, 0.f};

  int nkt = K >> 6;
  for (int kt = 0; kt < nkt; kt++) {
    __syncthreads();
#pragma unroll
    for (int i = 0; i < 4; i++) {
      int iw = w * 4 + i;           // wave-uniform
      int row = iw * 8 + sr;        // per-lane
      gload_lds16(A + (size_t)(m0 + row) * K + kt * 64 + sc * 8, &sA[iw * 512]);
      gload_lds16(Bt + (size_t)(n0 + row) * K + kt * 64 + sc * 8, &sB[iw * 512]);
    }
    __syncthreads();
#pragma unroll
    for (int ks = 0; ks < 2; ks++) {
      bf16x8 af[4], bfr[4];
#pragma unroll
      for (int mf = 0; mf < 4; mf++)
        af[mf] = *(const bf16x8*)&sA[(wr * 64 + mf * 16 + l15) * 64 + ks * 32 + lg * 8];
#pragma unroll
      for (int nf = 0; nf < 4; nf++)
        bfr[nf] = *(const bf16x8*)&sB[(wc * 64 + nf * 16 + l15) * 64 + ks * 32 + lg * 8];
#pragma unroll
      for (int mf = 0; mf < 4; mf++)
#pragma unroll
        for (int nf = 0; nf < 4; nf++)
          acc[mf][nf] = MFMA_16x16x32(af[mf], bfr[nf], acc[mf][nf]);
    }
  }

#pragma unroll
  for (int mf = 0; mf < 4; mf++) {
#pragma unroll
    for (int nf = 0; nf < 4; nf++) {
      int col = n0 + wc * 64 + nf * 16 + l15;
      int row0 = m0 + wr * 64 + mf * 16 + lg * 4;
      float biasv = bias[col];
      if (EPI == 0) {
        bf16* out = (bf16*)Cout;
#pragma unroll
        for (int r = 0; r < 4; r++)
          out[(size_t)(row0 + r) * N + col] = (bf16)(acc[mf][nf][r] + biasv);
      } else if (EPI == 1) {
        // col -> (h, d); token row0..row0+3 -> (b, n..n+3) contiguous
        bf16* out = (bf16*)Cout;
        int hh = col / 192, dd = col % 192;
        int bi = row0 >> 11, nn = row0 & 2047;
        bf16x4 pk = {(bf16)(acc[mf][nf][0] + biasv), (bf16)(acc[mf][nf][1] + biasv),
                     (bf16)(acc[mf][nf][2] + biasv), (bf16)(acc[mf][nf][3] + biasv)};
        *(bf16x4*)(out + (((size_t)bi * 16 + hh) * 192 + dd) * 2048 + nn) = pk;
      } else {
        float* out = (float*)Cout;
#pragma unroll
        for (int r = 0; r < 4; r++)
          out[(size_t)(row0 + r) * N + col] = acc[mf][nf][r] + biasv;
      }
    }
  }
}

// ---------------------------------------------------------------------------
// Flash attention, swapped-S^T form.
// Q,K: [4096][3072] bf16 (head slice at h*192, row stride 3072).
// Vt: [32][192][2048] bf16.  inter out: [4096][3072] bf16.
// Grid 512 = 32 (b,h) x 16 q-tiles of 128 rows; XCD-swizzled so each XCD owns
// 4 heads (K/V stay in its L2).  4 waves x 32 q-rows.  KBLK = 64.
// S^T = mfma(K,Q) -> per-lane P rows; softmax in-register (2-step shfl);
// P^T B-frags built via pack + ds_bpermute; O^T accum; T13 defer-max; T14
// next-tile prefetch issued before the PV MFMA phase.
// ---------------------------------------------------------------------------
__global__ __launch_bounds__(256, 2) void attn_kernel(const bf16* __restrict__ Q,
                                                      const bf16* __restrict__ Km,
                                                      const bf16* __restrict__ Vt,
                                                      bf16* __restrict__ inter) {
  __shared__ __align__(16) bf16 sK[64][200];  // 64 keys x 192 d (+8 pad)
  __shared__ __align__(16) bf16 sV[192][72];  // 192 d x 64 keys (+8 pad)

  // XCD swizzle: dispatch index i -> XCD i%8; give each XCD 4 whole heads.
  int i = blockIdx.x;
  int j = i >> 3;
  int bh = (i & 7) * 4 + (j >> 4);
  int qt = j & 15;
  int b = bh >> 4, h = bh & 15;
  int tid = threadIdx.x, lane = tid & 63, w = tid >> 6;
  int l15 = lane & 15, lg = lane >> 4;

  const bf16* Qh = Q + (size_t)b * 2048 * 3072 + (size_t)h * 192;
  const bf16* Kh = Km + (size_t)b * 2048 * 3072 + (size_t)h * 192;
  const bf16* Vh = Vt + (size_t)bh * 192 * 2048;

  int q0 = qt * 128 + w * 32;

  // Q fragments in registers for the whole kernel: 2 row-frags x 6 k-chunks.
  // (Also serves as the B-operand of the swapped QK^T: layout is identical.)
  bf16x8 aq[2][6];
#pragma unroll
  for (int rf = 0; rf < 2; rf++)
#pragma unroll
    for (int kc = 0; kc < 6; kc++)
      aq[rf][kc] = *(const bf16x8*)(Qh + (size_t)(q0 + rf * 16 + l15) * 3072 + kc * 32 + lg * 8);

  // O^T accumulator: o[rf][df] holds O^T[d = df*16+lg*4+r][q = rf*16+l15]
  f32x4 o[2][12];
#pragma unroll
  for (int rf = 0; rf < 2; rf++)
#pragma unroll
    for (int df = 0; df < 12; df++) o[rf][df] = (f32x4){0.f, 0.f, 0.f, 0.f};
  float mrow[2] = {-1e30f, -1e30f};  // running max (scaled domain), per q=l15
  float lrow[2] = {0.f, 0.f};

  const float scale = 0.03125f;  // 1/sqrt(1024)

  uint4 rk[6], rv[6];
#define LOAD_KV(KT)                                                                     \
  {                                                                                     \
    int kb = (KT) * 64;                                                                 \
    _Pragma("unroll") for (int ii = 0; ii < 6; ii++) {                                  \
      int id = tid + 256 * ii;                                                          \
      rk[ii] = *(const uint4*)(Kh + (size_t)(kb + id / 24) * 3072 + (id % 24) * 8);     \
      rv[ii] = *(const uint4*)(Vh + (size_t)(id >> 3) * 2048 + kb + (id & 7) * 8);      \
    }                                                                                   \
  }

  LOAD_KV(0);

  int srcA = l15 + ((lane & 16) << 1);
  bool h5 = (lane & 32) != 0;

  for (int kt = 0; kt < 32; kt++) {
    __syncthreads();  // previous iter done reading LDS
#pragma unroll
    for (int ii = 0; ii < 6; ii++) {
      int id = tid + 256 * ii;
      *(uint4*)&sK[id / 24][(id % 24) * 8] = rk[ii];
      *(uint4*)&sV[id >> 3][(id & 7) * 8] = rv[ii];
    }
    __syncthreads();  // tile visible

    // ---- S^T = K Q^T  (same LDS reads as before, operands swapped)
    f32x4 st[4][2];
#pragma unroll
    for (int kf = 0; kf < 4; kf++)
#pragma unroll
      for (int rf = 0; rf < 2; rf++) st[kf][rf] = (f32x4){0.f, 0.f, 0.f, 0.f};
    __builtin_amdgcn_s_setprio(1);
#pragma unroll
    for (int kc = 0; kc < 6; kc++) {
#pragma unroll
      for (int kf = 0; kf < 4; kf++) {
        bf16x8 bk = *(const bf16x8*)&sK[kf * 16 + l15][kc * 32 + lg * 8];
        st[kf][0] = MFMA_16x16x32(bk, aq[0][kc], st[kf][0]);
        st[kf][1] = MFMA_16x16x32(bk, aq[1][kc], st[kf][1]);
      }
    }
    __builtin_amdgcn_s_setprio(0);

    // ---- in-register softmax + P^T fragment build
    bf16x8 pf[2][2];
#pragma unroll
    for (int rf = 0; rf < 2; rf++) {
      // local max over the 16 keys this lane holds, then reduce across lg
      float pmx = st[0][rf][0];
#pragma unroll
      for (int kf = 0; kf < 4; kf++)
#pragma unroll
        for (int r = 0; r < 4; r++) pmx = fmaxf(pmx, st[kf][rf][r]);
      pmx = fmaxf(pmx, __shfl_xor(pmx, 16));
      pmx = fmaxf(pmx, __shfl_xor(pmx, 32));
      float pms = pmx * scale;

      float mn = mrow[rf];
      if (!__all(pms - mrow[rf] <= 8.0f)) {  // T13 defer-max
        mn = fmaxf(mrow[rf], pms);
        float corr = __expf(mrow[rf] - mn);
        mrow[rf] = mn;
        lrow[rf] *= corr;
#pragma unroll
        for (int df = 0; df < 12; df++) o[rf][df] *= corr;
      }

      float rs = 0.f;
#pragma unroll
      for (int kf = 0; kf < 4; kf++)
#pragma unroll
        for (int r = 0; r < 4; r++) {
          float p = __expf(fmaf(st[kf][rf][r], scale, -mn));
          st[kf][rf][r] = p;
          rs += p;
        }
      rs += __shfl_xor(rs, 16);
      rs += __shfl_xor(rs, 32);
      lrow[rf] += rs;

      // pack P rows to bf16 pairs: lane (l15,lg') holds keys 16kf+4lg'+{0..3}
      uint32_t pl[4], ph[4];
#pragma unroll
      for (int kf = 0; kf < 4; kf++) {
        pl[kf] = pack2(st[kf][rf][0], st[kf][rf][1]);
        ph[kf] = pack2(st[kf][rf][2], st[kf][rf][3]);
      }
      // B-frag: lane (l15,lg) needs keys ks*32+8lg..+7 for q=l15
#pragma unroll
      for (int ks = 0; ks < 2; ks++) {
        uint32_t A0a = __shfl((int)pl[2 * ks], srcA);
        uint32_t A0b = __shfl((int)pl[2 * ks + 1], srcA);
        uint32_t A1a = __shfl((int)ph[2 * ks], srcA);
        uint32_t A1b = __shfl((int)ph[2 * ks + 1], srcA);
        uint32_t B0a = __shfl((int)pl[2 * ks], srcA + 16);
        uint32_t B0b = __shfl((int)pl[2 * ks + 1], srcA + 16);
        uint32_t B1a = __shfl((int)ph[2 * ks], srcA + 16);
        uint32_t B1b = __shfl((int)ph[2 * ks + 1], srcA + 16);
        union { uint32_t u[4]; bf16x8 v; } fb;
        fb.u[0] = h5 ? A0b : A0a;
        fb.u[1] = h5 ? A1b : A1a;
        fb.u[2] = h5 ? B0b : B0a;
        fb.u[3] = h5 ? B1b : B1a;
        pf[rf][ks] = fb.v;
      }
    }

    // ---- T14: issue next tile's global loads; latency hides under PV
    if (kt < 31) LOAD_KV(kt + 1);

    // ---- O^T += V^T P^T
    __builtin_amdgcn_s_setprio(1);
#pragma unroll
    for (int ks = 0; ks < 2; ks++) {
#pragma unroll
      for (int df = 0; df < 12; df++) {
        bf16x8 av = *(const bf16x8*)&sV[df * 16 + l15][ks * 32 + lg * 8];
        o[0][df] = MFMA_16x16x32(av, pf[0][ks], o[0][df]);
        o[1][df] = MFMA_16x16x32(av, pf[1][ks], o[1][df]);
      }
    }
    __builtin_amdgcn_s_setprio(0);
  }

  // ---- epilogue: normalize, vectorized bf16x4 stores (d contiguous per lane)
#pragma unroll
  for (int rf = 0; rf < 2; rf++) {
    float inv = 1.0f / lrow[rf];
    size_t token = (size_t)b * 2048 + q0 + rf * 16 + l15;
    bf16* outp = inter + token * 3072 + h * 192 + lg * 4;
#pragma unroll
    for (int df = 0; df < 12; df++) {
      bf16x4 pk = {(bf16)(o[rf][df][0] * inv), (bf16)(o[rf][df][1] * inv),
                   (bf16)(o[rf][df][2] * inv), (bf16)(o[rf][df][3] * inv)};
      *(bf16x4*)(outp + df * 16) = pk;
    }
  }
#undef LOAD_KV
}

// ---------------------------------------------------------------------------
extern "C" void kernel_launch(void* const* d_in, const int* in_sizes, int n_in,
                              void* d_out, int out_size, void* d_ws, size_t ws_size,
                              hipStream_t stream) {
  const float* X = (const float*)d_in[0];
  const float* q_w = (const float*)d_in[1];
  const float* q_b = (const float*)d_in[2];
  const float* k_w = (const float*)d_in[3];
  const float* k_b = (const float*)d_in[4];
  const float* v_w = (const float*)d_in[5];
  const float* v_b = (const float*)d_in[6];
  const float* o_w = (const float*)d_in[7];
  const float* o_b = (const float*)d_in[8];

  char* ws = (char*)d_ws;
  bf16* Xb  = (bf16*)(ws);                    //  8 MiB: X bf16 [4096][1024]
  bf16* Wqt = (bf16*)(ws + 8388608);          //  6 MiB: q_w^T [3072][1024]
  bf16* Wvt = (bf16*)(ws + 14680064);         //  6 MiB: v_w^T (-> k_mat)
  bf16* Wkt = (bf16*)(ws + 20971520);         //  6 MiB: k_w^T (-> v_mat)
  bf16* Wot = (bf16*)(ws + 27262976);         //  6 MiB: o_w^T [1024][3072]
  bf16* Qm  = (bf16*)(ws + 33554432);         // 24 MiB: Q [4096][3072]
  bf16* Km  = (bf16*)(ws + 58720256);         // 24 MiB: K-attn [4096][3072]
  bf16* Vtw = (bf16*)(ws + 83886080);         // 24 MiB: V-attn^T [32][192][2048]
  bf16* Im  = (bf16*)(ws + 109051904);        // 24 MiB: inter [4096][3072]

  cvt_x_kernel<<<4096, 256, 0, stream>>>(X, Xb);
  transpose_cvt_kernel<<<3072, 256, 0, stream>>>(q_w, Wqt, 1024, 3072);
  transpose_cvt_kernel<<<3072, 256, 0, stream>>>(v_w, Wvt, 1024, 3072);
  transpose_cvt_kernel<<<3072, 256, 0, stream>>>(k_w, Wkt, 1024, 3072);
  transpose_cvt_kernel<<<3072, 256, 0, stream>>>(o_w, Wot, 3072, 1024);

  // quirk: k_mat uses v_w/v_b, v_mat uses k_w/k_b
  gemm_bf16_kernel<0><<<768, 256, 0, stream>>>(Xb, Wqt, q_b, Qm, 4096, 3072, 1024);
  gemm_bf16_kernel<0><<<768, 256, 0, stream>>>(Xb, Wvt, v_b, Km, 4096, 3072, 1024);
  gemm_bf16_kernel<1><<<768, 256, 0, stream>>>(Xb, Wkt, k_b, Vtw, 4096, 3072, 1024);

  attn_kernel<<<512, 256, 0, stream>>>(Qm, Km, Vtw, Im);

  gemm_bf16_kernel<2><<<256, 256, 0, stream>>>(Im, Wot, o_b, d_out, 4096, 1024, 3072);
}

// Round 4
// 489.692 us; speedup vs baseline: 1.2572x; 1.0008x over previous
//
#include <hip/hip_runtime.h>
#include <cstdint>
#include <cstddef>

typedef __bf16 bf16;
typedef __attribute__((ext_vector_type(8))) __bf16 bf16x8;
typedef __attribute__((ext_vector_type(4))) __bf16 bf16x4;
typedef __attribute__((ext_vector_type(2))) __bf16 bf16x2;
typedef __attribute__((ext_vector_type(4))) float f32x4;

#define MFMA_16x16x32(a, b, c) __builtin_amdgcn_mfma_f32_16x16x32_bf16((a), (b), (c), 0, 0, 0)

__device__ __forceinline__ void gload_lds16(const void* g, void* l) {
  __builtin_amdgcn_global_load_lds((__attribute__((address_space(1))) void*)g,
                                   (__attribute__((address_space(3))) void*)l,
                                   16, 0, 0);
}

// ---------------------------------------------------------------------------
// fp32 -> bf16 convert (grid covers exactly n/4 elements, n = 4096*1024)
// ---------------------------------------------------------------------------
__global__ __launch_bounds__(256) void cvt_x_kernel(const float* __restrict__ in,
                                                    bf16* __restrict__ out) {
  int i = blockIdx.x * 256 + threadIdx.x;
  float4 v = ((const float4*)in)[i];
  bf16x4 o = {(bf16)v.x, (bf16)v.y, (bf16)v.z, (bf16)v.w};
  ((bf16x4*)out)[i] = o;
}

// ---------------------------------------------------------------------------
// transpose + convert: in fp32 [R][C] -> out bf16 [C][R]
// ---------------------------------------------------------------------------
__global__ __launch_bounds__(256) void transpose_cvt_kernel(const float* __restrict__ in,
                                                            bf16* __restrict__ out,
                                                            int R, int C) {
  __shared__ float tile[32][33];
  int tiles_c = C >> 5;
  int br = (int)blockIdx.x / tiles_c, bc = (int)blockIdx.x % tiles_c;
  int r0 = br << 5, c0 = bc << 5;
  int tr = threadIdx.x >> 5, tc = threadIdx.x & 31;
#pragma unroll
  for (int i = 0; i < 4; i++)
    tile[tr + 8 * i][tc] = in[(size_t)(r0 + tr + 8 * i) * C + c0 + tc];
  __syncthreads();
#pragma unroll
  for (int i = 0; i < 4; i++) {
    int oc = tr + 8 * i;
    out[(size_t)(c0 + oc) * R + r0 + tc] = (bf16)tile[tc][oc];
  }
}

// ---------------------------------------------------------------------------
// bf16 GEMM: C[m][n] = sum_k A[m][k] * Bt[n][k] + bias[n]
// 128x128 tile, BK=64, 4 waves (2x2), mfma_f32_16x16x32_bf16, global_load_lds.
// EPI 0: bf16 out [M][N].  EPI 1: bf16 out transposed per head ->
//        Vt[b][h][192][2048] (N==3072, token rows).  EPI 2: fp32 out [M][N].
// ---------------------------------------------------------------------------
template <int EPI>
__global__ __launch_bounds__(256, 2) void gemm_bf16_kernel(const bf16* __restrict__ A,
                                                           const bf16* __restrict__ Bt,
                                                           const float* __restrict__ bias,
                                                           void* __restrict__ Cout,
                                                           int M, int N, int K) {
  __shared__ __align__(16) bf16 sA[128 * 64];
  __shared__ __align__(16) bf16 sB[128 * 64];
  int tiles_n = N >> 7;
  int bm = (int)blockIdx.x / tiles_n, bn = (int)blockIdx.x % tiles_n;
  int m0 = bm << 7, n0 = bn << 7;
  int tid = threadIdx.x, lane = tid & 63, w = tid >> 6;
  int wr = w >> 1, wc = w & 1;
  int l15 = lane & 15, lg = lane >> 4;
  int sr = lane >> 3, sc = lane & 7;  // staging: 8 lanes per 64-elem row

  f32x4 acc[4][4];
#pragma unroll
  for (int mf = 0; mf < 4; mf++)
#pragma unroll
    for (int nf = 0; nf < 4; nf++) acc[mf][nf] = (f32x4){0.f, 0.f, 0.f, 0.f};

  int nkt = K >> 6;
  for (int kt = 0; kt < nkt; kt++) {
    __syncthreads();
#pragma unroll
    for (int i = 0; i < 4; i++) {
      int iw = w * 4 + i;           // wave-uniform
      int row = iw * 8 + sr;        // per-lane
      gload_lds16(A + (size_t)(m0 + row) * K + kt * 64 + sc * 8, &sA[iw * 512]);
      gload_lds16(Bt + (size_t)(n0 + row) * K + kt * 64 + sc * 8, &sB[iw * 512]);
    }
    __syncthreads();
#pragma unroll
    for (int ks = 0; ks < 2; ks++) {
      bf16x8 af[4], bfr[4];
#pragma unroll
      for (int mf = 0; mf < 4; mf++)
        af[mf] = *(const bf16x8*)&sA[(wr * 64 + mf * 16 + l15) * 64 + ks * 32 + lg * 8];
#pragma unroll
      for (int nf = 0; nf < 4; nf++)
        bfr[nf] = *(const bf16x8*)&sB[(wc * 64 + nf * 16 + l15) * 64 + ks * 32 + lg * 8];
#pragma unroll
      for (int mf = 0; mf < 4; mf++)
#pragma unroll
        for (int nf = 0; nf < 4; nf++)
          acc[mf][nf] = MFMA_16x16x32(af[mf], bfr[nf], acc[mf][nf]);
    }
  }

#pragma unroll
  for (int mf = 0; mf < 4; mf++) {
#pragma unroll
    for (int nf = 0; nf < 4; nf++) {
      int col = n0 + wc * 64 + nf * 16 + l15;
      int row0 = m0 + wr * 64 + mf * 16 + lg * 4;
      float biasv = bias[col];
      if (EPI == 0) {
        bf16* out = (bf16*)Cout;
#pragma unroll
        for (int r = 0; r < 4; r++)
          out[(size_t)(row0 + r) * N + col] = (bf16)(acc[mf][nf][r] + biasv);
      } else if (EPI == 1) {
        // col -> (h, d); token row0..row0+3 -> (b, n..n+3) contiguous
        bf16* out = (bf16*)Cout;
        int hh = col / 192, dd = col % 192;
        int bi = row0 >> 11, nn = row0 & 2047;
        bf16x4 pk = {(bf16)(acc[mf][nf][0] + biasv), (bf16)(acc[mf][nf][1] + biasv),
                     (bf16)(acc[mf][nf][2] + biasv), (bf16)(acc[mf][nf][3] + biasv)};
        *(bf16x4*)(out + (((size_t)bi * 16 + hh) * 192 + dd) * 2048 + nn) = pk;
      } else {
        float* out = (float*)Cout;
#pragma unroll
        for (int r = 0; r < 4; r++)
          out[(size_t)(row0 + r) * N + col] = acc[mf][nf][r] + biasv;
      }
    }
  }
}

// ---------------------------------------------------------------------------
// Flash attention, swapped-S^T form, LDS P^T round-trip (no bpermute chains).
// Q,K: [4096][3072] bf16 (head slice at h*192, row stride 3072).
// Vt: [32][192][2048] bf16.  inter out: [4096][3072] bf16.
// Grid 512, XCD-swizzled (each XCD owns 4 heads -> K/V L2-resident).
// 4 waves x 32 q-rows, KBLK=64.  Softmax in exp2 domain, tree reductions.
// P^T goes through a per-wave padded LDS tile in exact B-frag layout:
// 8 ds_write_b64 + 4 ds_read_b128 per iter (replaces 32 serial bpermutes).
// ---------------------------------------------------------------------------
__global__ __launch_bounds__(256, 2) void attn_kernel(const bf16* __restrict__ Q,
                                                      const bf16* __restrict__ Km,
                                                      const bf16* __restrict__ Vt,
                                                      bf16* __restrict__ inter) {
  __shared__ __align__(16) bf16 sK[64][200];   // 64 keys x 192 d (+8 pad)
  __shared__ __align__(16) bf16 sV[192][72];   // 192 d x 64 keys (+8 pad)
  __shared__ __align__(16) bf16 sPT[4 * 2 * 16 * 72];  // per-wave P^T [rf][q=16][64+8]

  // XCD swizzle: dispatch index i -> XCD i%8; give each XCD 4 whole heads.
  int i = blockIdx.x;
  int j = i >> 3;
  int bh = (i & 7) * 4 + (j >> 4);
  int qt = j & 15;
  int b = bh >> 4, h = bh & 15;
  int tid = threadIdx.x, lane = tid & 63, w = tid >> 6;
  int l15 = lane & 15, lg = lane >> 4;

  const bf16* Qh = Q + (size_t)b * 2048 * 3072 + (size_t)h * 192;
  const bf16* Kh = Km + (size_t)b * 2048 * 3072 + (size_t)h * 192;
  const bf16* Vh = Vt + (size_t)bh * 192 * 2048;

  int q0 = qt * 128 + w * 32;

  // Q fragments in registers for the whole kernel (B-operand of swapped QK^T)
  bf16x8 aq[2][6];
#pragma unroll
  for (int rf = 0; rf < 2; rf++)
#pragma unroll
    for (int kc = 0; kc < 6; kc++)
      aq[rf][kc] = *(const bf16x8*)(Qh + (size_t)(q0 + rf * 16 + l15) * 3072 + kc * 32 + lg * 8);

  // O^T accumulator: o[rf][df] holds O^T[d = df*16+lg*4+r][q = rf*16+l15]
  f32x4 o[2][12];
#pragma unroll
  for (int rf = 0; rf < 2; rf++)
#pragma unroll
    for (int df = 0; df < 12; df++) o[rf][df] = (f32x4){0.f, 0.f, 0.f, 0.f};
  float mrow[2] = {-1e30f, -1e30f};  // running max, exp2-domain (scl2 * s)
  float lrow[2] = {0.f, 0.f};

  const float scl2 = 0.03125f * 1.44269504f;  // (1/sqrt(1024)) * log2(e)

  // hoisted per-lane staging offsets (elements)
  int kOff[6], vOff[6];
#pragma unroll
  for (int ii = 0; ii < 6; ii++) {
    int id = tid + 256 * ii;
    kOff[ii] = (id / 24) * 3072 + (id % 24) * 8;
    vOff[ii] = (id >> 3) * 2048 + (id & 7) * 8;
  }

  uint4 rk[6], rv[6];
#define LOAD_KV(KT)                                                     \
  {                                                                     \
    int kb = (KT) * 64;                                                 \
    _Pragma("unroll") for (int ii = 0; ii < 6; ii++) {                  \
      rk[ii] = *(const uint4*)(Kh + (size_t)kb * 3072 + kOff[ii]);      \
      rv[ii] = *(const uint4*)(Vh + kb + vOff[ii]);                     \
    }                                                                   \
  }

  LOAD_KV(0);

  bf16* myPT0 = &sPT[((w * 2 + 0) * 16 + l15) * 72];
  bf16* myPT1 = &sPT[((w * 2 + 1) * 16 + l15) * 72];

  for (int kt = 0; kt < 32; kt++) {
    __syncthreads();  // previous iter done reading sK/sV
#pragma unroll
    for (int ii = 0; ii < 6; ii++) {
      int id = tid + 256 * ii;
      *(uint4*)&sK[id / 24][(id % 24) * 8] = rk[ii];
      *(uint4*)&sV[id >> 3][(id & 7) * 8] = rv[ii];
    }
    __syncthreads();  // tile visible

    // ---- S^T = K Q^T
    f32x4 st[4][2];
#pragma unroll
    for (int kf = 0; kf < 4; kf++)
#pragma unroll
      for (int rf = 0; rf < 2; rf++) st[kf][rf] = (f32x4){0.f, 0.f, 0.f, 0.f};
    __builtin_amdgcn_s_setprio(1);
#pragma unroll
    for (int kc = 0; kc < 6; kc++) {
#pragma unroll
      for (int kf = 0; kf < 4; kf++) {
        bf16x8 bk = *(const bf16x8*)&sK[kf * 16 + l15][kc * 32 + lg * 8];
        st[kf][0] = MFMA_16x16x32(bk, aq[0][kc], st[kf][0]);
        st[kf][1] = MFMA_16x16x32(bk, aq[1][kc], st[kf][1]);
      }
    }
    __builtin_amdgcn_s_setprio(0);

    // ---- T14: issue next tile's loads now; latency hides under SM+PV
    if (kt < 31) LOAD_KV(kt + 1);

    // ---- softmax (exp2 domain, tree reductions) + P^T -> per-wave LDS
#pragma unroll
    for (int rf = 0; rf < 2; rf++) {
      bf16* myPT = rf ? myPT1 : myPT0;
      float mk[4];
#pragma unroll
      for (int kf = 0; kf < 4; kf++)
        mk[kf] = fmaxf(fmaxf(st[kf][rf][0], st[kf][rf][1]),
                       fmaxf(st[kf][rf][2], st[kf][rf][3]));
      float pmx = fmaxf(fmaxf(mk[0], mk[1]), fmaxf(mk[2], mk[3]));
      pmx = fmaxf(pmx, __shfl_xor(pmx, 16));
      pmx = fmaxf(pmx, __shfl_xor(pmx, 32));
      float pms = pmx * scl2;

      float mn = mrow[rf];
      if (!__all(pms - mn <= 11.0f)) {  // T13 defer-max (exp2 domain, ~e^7.6)
        mn = fmaxf(mn, pms);
        float corr = exp2f(mrow[rf] - mn);
        mrow[rf] = mn;
        lrow[rf] *= corr;
#pragma unroll
        for (int df = 0; df < 12; df++) o[rf][df] *= corr;
      }

      float skf[4];
#pragma unroll
      for (int kf = 0; kf < 4; kf++) {
        float e0 = exp2f(fmaf(st[kf][rf][0], scl2, -mn));
        float e1 = exp2f(fmaf(st[kf][rf][1], scl2, -mn));
        float e2 = exp2f(fmaf(st[kf][rf][2], scl2, -mn));
        float e3 = exp2f(fmaf(st[kf][rf][3], scl2, -mn));
        skf[kf] = (e0 + e1) + (e2 + e3);
        bf16x4 pk4 = {(bf16)e0, (bf16)e1, (bf16)e2, (bf16)e3};
        *(bf16x4*)&myPT[kf * 16 + 4 * lg] = pk4;  // keys kf*16+4lg.. for q=l15
      }
      float rs = (skf[0] + skf[1]) + (skf[2] + skf[3]);
      rs += __shfl_xor(rs, 16);
      rs += __shfl_xor(rs, 32);
      lrow[rf] += rs;
    }

    // ---- read P^T B-frags (exact MFMA layout): 4 x ds_read_b128
    bf16x8 pf[2][2];
#pragma unroll
    for (int rf = 0; rf < 2; rf++) {
      bf16* myPT = rf ? myPT1 : myPT0;
#pragma unroll
      for (int ks = 0; ks < 2; ks++)
        pf[rf][ks] = *(const bf16x8*)&myPT[ks * 32 + lg * 8];
    }

    // ---- O^T += V^T P^T
    __builtin_amdgcn_s_setprio(1);
#pragma unroll
    for (int ks = 0; ks < 2; ks++) {
#pragma unroll
      for (int df = 0; df < 12; df++) {
        bf16x8 av = *(const bf16x8*)&sV[df * 16 + l15][ks * 32 + lg * 8];
        o[0][df] = MFMA_16x16x32(av, pf[0][ks], o[0][df]);
        o[1][df] = MFMA_16x16x32(av, pf[1][ks], o[1][df]);
      }
    }
    __builtin_amdgcn_s_setprio(0);
  }

  // ---- epilogue: normalize, vectorized bf16x4 stores (d contiguous per lane)
#pragma unroll
  for (int rf = 0; rf < 2; rf++) {
    float inv = 1.0f / lrow[rf];
    size_t token = (size_t)b * 2048 + q0 + rf * 16 + l15;
    bf16* outp = inter + token * 3072 + h * 192 + lg * 4;
#pragma unroll
    for (int df = 0; df < 12; df++) {
      bf16x4 pk = {(bf16)(o[rf][df][0] * inv), (bf16)(o[rf][df][1] * inv),
                   (bf16)(o[rf][df][2] * inv), (bf16)(o[rf][df][3] * inv)};
      *(bf16x4*)(outp + df * 16) = pk;
    }
  }
#undef LOAD_KV
}

// ---------------------------------------------------------------------------
extern "C" void kernel_launch(void* const* d_in, const int* in_sizes, int n_in,
                              void* d_out, int out_size, void* d_ws, size_t ws_size,
                              hipStream_t stream) {
  const float* X = (const float*)d_in[0];
  const float* q_w = (const float*)d_in[1];
  const float* q_b = (const float*)d_in[2];
  const float* k_w = (const float*)d_in[3];
  const float* k_b = (const float*)d_in[4];
  const float* v_w = (const float*)d_in[5];
  const float* v_b = (const float*)d_in[6];
  const float* o_w = (const float*)d_in[7];
  const float* o_b = (const float*)d_in[8];

  char* ws = (char*)d_ws;
  bf16* Xb  = (bf16*)(ws);                    //  8 MiB: X bf16 [4096][1024]
  bf16* Wqt = (bf16*)(ws + 8388608);          //  6 MiB: q_w^T [3072][1024]
  bf16* Wvt = (bf16*)(ws + 14680064);         //  6 MiB: v_w^T (-> k_mat)
  bf16* Wkt = (bf16*)(ws + 20971520);         //  6 MiB: k_w^T (-> v_mat)
  bf16* Wot = (bf16*)(ws + 27262976);         //  6 MiB: o_w^T [1024][3072]
  bf16* Qm  = (bf16*)(ws + 33554432);         // 24 MiB: Q [4096][3072]
  bf16* Km  = (bf16*)(ws + 58720256);         // 24 MiB: K-attn [4096][3072]
  bf16* Vtw = (bf16*)(ws + 83886080);         // 24 MiB: V-attn^T [32][192][2048]
  bf16* Im  = (bf16*)(ws + 109051904);        // 24 MiB: inter [4096][3072]

  cvt_x_kernel<<<4096, 256, 0, stream>>>(X, Xb);
  transpose_cvt_kernel<<<3072, 256, 0, stream>>>(q_w, Wqt, 1024, 3072);
  transpose_cvt_kernel<<<3072, 256, 0, stream>>>(v_w, Wvt, 1024, 3072);
  transpose_cvt_kernel<<<3072, 256, 0, stream>>>(k_w, Wkt, 1024, 3072);
  transpose_cvt_kernel<<<3072, 256, 0, stream>>>(o_w, Wot, 3072, 1024);

  // quirk: k_mat uses v_w/v_b, v_mat uses k_w/k_b
  gemm_bf16_kernel<0><<<768, 256, 0, stream>>>(Xb, Wqt, q_b, Qm, 4096, 3072, 1024);
  gemm_bf16_kernel<0><<<768, 256, 0, stream>>>(Xb, Wvt, v_b, Km, 4096, 3072, 1024);
  gemm_bf16_kernel<1><<<768, 256, 0, stream>>>(Xb, Wkt, k_b, Vtw, 4096, 3072, 1024);

  attn_kernel<<<512, 256, 0, stream>>>(Qm, Km, Vtw, Im);

  gemm_bf16_kernel<2><<<256, 256, 0, stream>>>(Im, Wot, o_b, d_out, 4096, 1024, 3072);
}

// Round 5
// 324.420 us; speedup vs baseline: 1.8977x; 1.5094x over previous
//
#include <hip/hip_runtime.h>
#include <cstdint>
#include <cstddef>

typedef __bf16 bf16;
typedef __attribute__((ext_vector_type(8))) __bf16 bf16x8;
typedef __attribute__((ext_vector_type(4))) __bf16 bf16x4;
typedef __attribute__((ext_vector_type(2))) __bf16 bf16x2;
typedef __attribute__((ext_vector_type(4))) float f32x4;

#define MFMA_16x16x32(a, b, c) __builtin_amdgcn_mfma_f32_16x16x32_bf16((a), (b), (c), 0, 0, 0)

__device__ __forceinline__ void gload_lds16(const void* g, void* l) {
  __builtin_amdgcn_global_load_lds((__attribute__((address_space(1))) void*)g,
                                   (__attribute__((address_space(3))) void*)l,
                                   16, 0, 0);
}

// ---------------------------------------------------------------------------
// fp32 -> bf16 convert (grid covers exactly n/4 elements, n = 4096*1024)
// ---------------------------------------------------------------------------
__global__ __launch_bounds__(256) void cvt_x_kernel(const float* __restrict__ in,
                                                    bf16* __restrict__ out) {
  int i = blockIdx.x * 256 + threadIdx.x;
  float4 v = ((const float4*)in)[i];
  bf16x4 o = {(bf16)v.x, (bf16)v.y, (bf16)v.z, (bf16)v.w};
  ((bf16x4*)out)[i] = o;
}

// ---------------------------------------------------------------------------
// transpose + convert: in fp32 [R][C] -> out bf16 [C][R]
// ---------------------------------------------------------------------------
__global__ __launch_bounds__(256) void transpose_cvt_kernel(const float* __restrict__ in,
                                                            bf16* __restrict__ out,
                                                            int R, int C) {
  __shared__ float tile[32][33];
  int tiles_c = C >> 5;
  int br = (int)blockIdx.x / tiles_c, bc = (int)blockIdx.x % tiles_c;
  int r0 = br << 5, c0 = bc << 5;
  int tr = threadIdx.x >> 5, tc = threadIdx.x & 31;
#pragma unroll
  for (int i = 0; i < 4; i++)
    tile[tr + 8 * i][tc] = in[(size_t)(r0 + tr + 8 * i) * C + c0 + tc];
  __syncthreads();
#pragma unroll
  for (int i = 0; i < 4; i++) {
    int oc = tr + 8 * i;
    out[(size_t)(c0 + oc) * R + r0 + tc] = (bf16)tile[tc][oc];
  }
}

// ---------------------------------------------------------------------------
// bf16 GEMM: C[m][n] = sum_k A[m][k] * Bt[n][k] + bias[n]
// 128x128 tile, BK=64, 4 waves (2x2), mfma_f32_16x16x32_bf16, global_load_lds.
// EPI 0: bf16 out [M][N].  EPI 1: bf16 out transposed per head ->
//        Vt[b][h][192][2048] (N==3072, token rows).  EPI 2: fp32 out [M][N].
// ---------------------------------------------------------------------------
template <int EPI>
__global__ __launch_bounds__(256, 2) void gemm_bf16_kernel(const bf16* __restrict__ A,
                                                           const bf16* __restrict__ Bt,
                                                           const float* __restrict__ bias,
                                                           void* __restrict__ Cout,
                                                           int M, int N, int K) {
  __shared__ __align__(16) bf16 sA[128 * 64];
  __shared__ __align__(16) bf16 sB[128 * 64];
  int tiles_n = N >> 7;
  int bm = (int)blockIdx.x / tiles_n, bn = (int)blockIdx.x % tiles_n;
  int m0 = bm << 7, n0 = bn << 7;
  int tid = threadIdx.x, lane = tid & 63, w = tid >> 6;
  int wr = w >> 1, wc = w & 1;
  int l15 = lane & 15, lg = lane >> 4;
  int sr = lane >> 3, sc = lane & 7;  // staging: 8 lanes per 64-elem row

  f32x4 acc[4][4];
#pragma unroll
  for (int mf = 0; mf < 4; mf++)
#pragma unroll
    for (int nf = 0; nf < 4; nf++) acc[mf][nf] = (f32x4){0.f, 0.f, 0.f, 0.f};

  int nkt = K >> 6;
  for (int kt = 0; kt < nkt; kt++) {
    __syncthreads();
#pragma unroll
    for (int i = 0; i < 4; i++) {
      int iw = w * 4 + i;           // wave-uniform
      int row = iw * 8 + sr;        // per-lane
      gload_lds16(A + (size_t)(m0 + row) * K + kt * 64 + sc * 8, &sA[iw * 512]);
      gload_lds16(Bt + (size_t)(n0 + row) * K + kt * 64 + sc * 8, &sB[iw * 512]);
    }
    __syncthreads();
#pragma unroll
    for (int ks = 0; ks < 2; ks++) {
      bf16x8 af[4], bfr[4];
#pragma unroll
      for (int mf = 0; mf < 4; mf++)
        af[mf] = *(const bf16x8*)&sA[(wr * 64 + mf * 16 + l15) * 64 + ks * 32 + lg * 8];
#pragma unroll
      for (int nf = 0; nf < 4; nf++)
        bfr[nf] = *(const bf16x8*)&sB[(wc * 64 + nf * 16 + l15) * 64 + ks * 32 + lg * 8];
#pragma unroll
      for (int mf = 0; mf < 4; mf++)
#pragma unroll
        for (int nf = 0; nf < 4; nf++)
          acc[mf][nf] = MFMA_16x16x32(af[mf], bfr[nf], acc[mf][nf]);
    }
  }

#pragma unroll
  for (int mf = 0; mf < 4; mf++) {
#pragma unroll
    for (int nf = 0; nf < 4; nf++) {
      int col = n0 + wc * 64 + nf * 16 + l15;
      int row0 = m0 + wr * 64 + mf * 16 + lg * 4;
      float biasv = bias[col];
      if (EPI == 0) {
        bf16* out = (bf16*)Cout;
#pragma unroll
        for (int r = 0; r < 4; r++)
          out[(size_t)(row0 + r) * N + col] = (bf16)(acc[mf][nf][r] + biasv);
      } else if (EPI == 1) {
        // col -> (h, d); token row0..row0+3 -> (b, n..n+3) contiguous
        bf16* out = (bf16*)Cout;
        int hh = col / 192, dd = col % 192;
        int bi = row0 >> 11, nn = row0 & 2047;
        bf16x4 pk = {(bf16)(acc[mf][nf][0] + biasv), (bf16)(acc[mf][nf][1] + biasv),
                     (bf16)(acc[mf][nf][2] + biasv), (bf16)(acc[mf][nf][3] + biasv)};
        *(bf16x4*)(out + (((size_t)bi * 16 + hh) * 192 + dd) * 2048 + nn) = pk;
      } else {
        float* out = (float*)Cout;
#pragma unroll
        for (int r = 0; r < 4; r++)
          out[(size_t)(row0 + r) * N + col] = acc[mf][nf][r] + biasv;
      }
    }
  }
}

// ---------------------------------------------------------------------------
// Flash attention, swapped-S^T, global_load_lds double-buffered K/V staging.
// 512 threads = 8 waves x 32 q-rows (QBLK=256); grid 256 = 1 block/CU.
// K tile [64][192] and V tile [192][64] staged DIRECT to linear LDS via
// global_load_lds; XOR swizzle (chunk ^= row&7 within 128B windows) applied
// on the GLOBAL SOURCE address and again on the LDS READ (G21 both-sides rule)
// -> bank-conflict-free ds_read_b128 without padding, zero staging registers
// (kills the 805 MB/dispatch spill traffic of rounds 1-4).
// One __syncthreads per iter: issue stage(t+1) -> compute buf(t) -> barrier.
// ---------------------------------------------------------------------------
__global__ __launch_bounds__(512, 2) void attn_kernel(const bf16* __restrict__ Q,
                                                      const bf16* __restrict__ Km,
                                                      const bf16* __restrict__ Vt,
                                                      bf16* __restrict__ inter) {
  __shared__ __align__(16) bf16 sK[2][64 * 192];   // linear, content swizzled
  __shared__ __align__(16) bf16 sV[2][192 * 64];   // linear, content swizzled
  __shared__ __align__(16) bf16 sPT[8 * 2 * 16 * 72];  // per-wave P^T, padded

  // XCD swizzle: block i -> XCD i%8; each XCD owns 4 whole heads.
  int i = blockIdx.x;
  int j = i >> 3;
  int bh = (i & 7) * 4 + (j >> 3);
  int qt = j & 7;
  int b = bh >> 4, h = bh & 15;
  int tid = threadIdx.x, lane = tid & 63, w = tid >> 6;
  int l15 = lane & 15, lg = lane >> 4;
  int swz = l15 & 7;

  const bf16* Qh = Q + (size_t)b * 2048 * 3072 + (size_t)h * 192;
  const bf16* Kh = Km + (size_t)b * 2048 * 3072 + (size_t)h * 192;
  const bf16* Vh = Vt + (size_t)bh * 192 * 2048;

  int q0 = qt * 256 + w * 32;

  // staging geometry: 24 KB per tile = 24 regions of 1 KB (64 lanes x 16B).
  // region r = ii*8 + w; chunk-slot s = r*64 + lane.
  int kOff[3], vOff[3], ldsOff[3];
#pragma unroll
  for (int ii = 0; ii < 3; ii++) {
    int r = ii * 8 + w;
    int s = r * 64 + lane;
    int krow = s / 24, kc = s % 24;                    // K: 24 chunks/row (384B)
    int kcs = (kc & 24) | ((kc & 7) ^ (krow & 7));     // inverse swizzle on src
    kOff[ii] = krow * 3072 + kcs * 8;
    int vrow = s >> 3, vc = s & 7;                     // V: 8 chunks/row (128B)
    int vcs = vc ^ (vrow & 7);
    vOff[ii] = vrow * 2048 + vcs * 8;
    ldsOff[ii] = r * 512;                              // elems (1 KB regions)
  }

#define STAGE(BUF, KT)                                                   \
  {                                                                      \
    int kb = (KT) * 64;                                                  \
    _Pragma("unroll") for (int ii = 0; ii < 3; ii++) {                   \
      gload_lds16(Kh + (size_t)kb * 3072 + kOff[ii], &sK[BUF][ldsOff[ii]]); \
      gload_lds16(Vh + kb + vOff[ii], &sV[BUF][ldsOff[ii]]);             \
    }                                                                    \
  }

  STAGE(0, 0);

  // Q fragments in registers for the whole kernel (B-operand of swapped QK^T)
  bf16x8 aq[2][6];
#pragma unroll
  for (int rf = 0; rf < 2; rf++)
#pragma unroll
    for (int kc = 0; kc < 6; kc++)
      aq[rf][kc] = *(const bf16x8*)(Qh + (size_t)(q0 + rf * 16 + l15) * 3072 + kc * 32 + lg * 8);

  // O^T accumulator: o[rf][df] holds O^T[d = df*16+lg*4+r][q = rf*16+l15]
  f32x4 o[2][12];
#pragma unroll
  for (int rf = 0; rf < 2; rf++)
#pragma unroll
    for (int df = 0; df < 12; df++) o[rf][df] = (f32x4){0.f, 0.f, 0.f, 0.f};
  float mrow[2] = {-1e30f, -1e30f};  // running max, exp2 domain
  float lrow[2] = {0.f, 0.f};

  const float scl2 = 0.03125f * 1.44269504f;  // (1/sqrt(1024)) * log2(e)

  bf16* myPT0 = &sPT[((w * 2 + 0) * 16 + l15) * 72];
  bf16* myPT1 = &sPT[((w * 2 + 1) * 16 + l15) * 72];

  __syncthreads();  // stage(0) landed (compiler drains vmcnt before barrier)

  for (int kt = 0; kt < 32; kt++) {
    const bf16* kbuf = sK[kt & 1];
    const bf16* vbuf = sV[kt & 1];
    if (kt < 31) STAGE((kt & 1) ^ 1, kt + 1);  // latency hides under compute

    // ---- S^T = K Q^T  (swizzled reads: chunk g -> g^swz within 128B window)
    f32x4 st[4][2];
#pragma unroll
    for (int kf = 0; kf < 4; kf++)
#pragma unroll
      for (int rf = 0; rf < 2; rf++) st[kf][rf] = (f32x4){0.f, 0.f, 0.f, 0.f};
    __builtin_amdgcn_s_setprio(1);
#pragma unroll
    for (int kc = 0; kc < 6; kc++) {
      int g = kc * 4 + lg;
      int cc = (g & 24) | ((g & 7) ^ swz);
#pragma unroll
      for (int kf = 0; kf < 4; kf++) {
        bf16x8 bk = *(const bf16x8*)&kbuf[(kf * 16 + l15) * 192 + cc * 8];
        st[kf][0] = MFMA_16x16x32(bk, aq[0][kc], st[kf][0]);
        st[kf][1] = MFMA_16x16x32(bk, aq[1][kc], st[kf][1]);
      }
    }
    __builtin_amdgcn_s_setprio(0);

    // ---- softmax (exp2 domain, tree reductions) + P^T -> per-wave LDS
#pragma unroll
    for (int rf = 0; rf < 2; rf++) {
      bf16* myPT = rf ? myPT1 : myPT0;
      float mk[4];
#pragma unroll
      for (int kf = 0; kf < 4; kf++)
        mk[kf] = fmaxf(fmaxf(st[kf][rf][0], st[kf][rf][1]),
                       fmaxf(st[kf][rf][2], st[kf][rf][3]));
      float pmx = fmaxf(fmaxf(mk[0], mk[1]), fmaxf(mk[2], mk[3]));
      pmx = fmaxf(pmx, __shfl_xor(pmx, 16));
      pmx = fmaxf(pmx, __shfl_xor(pmx, 32));
      float pms = pmx * scl2;

      float mn = mrow[rf];
      if (!__all(pms - mn <= 11.0f)) {  // T13 defer-max
        mn = fmaxf(mn, pms);
        float corr = exp2f(mrow[rf] - mn);
        mrow[rf] = mn;
        lrow[rf] *= corr;
#pragma unroll
        for (int df = 0; df < 12; df++) o[rf][df] *= corr;
      }

      float skf[4];
#pragma unroll
      for (int kf = 0; kf < 4; kf++) {
        float e0 = exp2f(fmaf(st[kf][rf][0], scl2, -mn));
        float e1 = exp2f(fmaf(st[kf][rf][1], scl2, -mn));
        float e2 = exp2f(fmaf(st[kf][rf][2], scl2, -mn));
        float e3 = exp2f(fmaf(st[kf][rf][3], scl2, -mn));
        skf[kf] = (e0 + e1) + (e2 + e3);
        bf16x4 pk4 = {(bf16)e0, (bf16)e1, (bf16)e2, (bf16)e3};
        *(bf16x4*)&myPT[kf * 16 + 4 * lg] = pk4;  // keys kf*16+4lg.. for q=l15
      }
      float rs = (skf[0] + skf[1]) + (skf[2] + skf[3]);
      rs += __shfl_xor(rs, 16);
      rs += __shfl_xor(rs, 32);
      lrow[rf] += rs;
    }

    // ---- read P^T B-frags (exact MFMA layout)
    bf16x8 pf[2][2];
#pragma unroll
    for (int rf = 0; rf < 2; rf++) {
      bf16* myPT = rf ? myPT1 : myPT0;
#pragma unroll
      for (int ks = 0; ks < 2; ks++)
        pf[rf][ks] = *(const bf16x8*)&myPT[ks * 32 + lg * 8];
    }

    // ---- O^T += V^T P^T  (swizzled V reads)
    __builtin_amdgcn_s_setprio(1);
#pragma unroll
    for (int ks = 0; ks < 2; ks++) {
      int cv = (ks * 4 + lg) ^ swz;
#pragma unroll
      for (int df = 0; df < 12; df++) {
        bf16x8 av = *(const bf16x8*)&vbuf[(df * 16 + l15) * 64 + cv * 8];
        o[0][df] = MFMA_16x16x32(av, pf[0][ks], o[0][df]);
        o[1][df] = MFMA_16x16x32(av, pf[1][ks], o[1][df]);
      }
    }
    __builtin_amdgcn_s_setprio(0);

    __syncthreads();  // drains stage(t+1) loads; all waves done reading buf(t)
  }

  // ---- epilogue: normalize, vectorized bf16x4 stores (d contiguous per lane)
#pragma unroll
  for (int rf = 0; rf < 2; rf++) {
    float inv = 1.0f / lrow[rf];
    size_t token = (size_t)b * 2048 + q0 + rf * 16 + l15;
    bf16* outp = inter + token * 3072 + h * 192 + lg * 4;
#pragma unroll
    for (int df = 0; df < 12; df++) {
      bf16x4 pk = {(bf16)(o[rf][df][0] * inv), (bf16)(o[rf][df][1] * inv),
                   (bf16)(o[rf][df][2] * inv), (bf16)(o[rf][df][3] * inv)};
      *(bf16x4*)(outp + df * 16) = pk;
    }
  }
#undef STAGE
}

// ---------------------------------------------------------------------------
extern "C" void kernel_launch(void* const* d_in, const int* in_sizes, int n_in,
                              void* d_out, int out_size, void* d_ws, size_t ws_size,
                              hipStream_t stream) {
  const float* X = (const float*)d_in[0];
  const float* q_w = (const float*)d_in[1];
  const float* q_b = (const float*)d_in[2];
  const float* k_w = (const float*)d_in[3];
  const float* k_b = (const float*)d_in[4];
  const float* v_w = (const float*)d_in[5];
  const float* v_b = (const float*)d_in[6];
  const float* o_w = (const float*)d_in[7];
  const float* o_b = (const float*)d_in[8];

  char* ws = (char*)d_ws;
  bf16* Xb  = (bf16*)(ws);                    //  8 MiB: X bf16 [4096][1024]
  bf16* Wqt = (bf16*)(ws + 8388608);          //  6 MiB: q_w^T [3072][1024]
  bf16* Wvt = (bf16*)(ws + 14680064);         //  6 MiB: v_w^T (-> k_mat)
  bf16* Wkt = (bf16*)(ws + 20971520);         //  6 MiB: k_w^T (-> v_mat)
  bf16* Wot = (bf16*)(ws + 27262976);         //  6 MiB: o_w^T [1024][3072]
  bf16* Qm  = (bf16*)(ws + 33554432);         // 24 MiB: Q [4096][3072]
  bf16* Km  = (bf16*)(ws + 58720256);         // 24 MiB: K-attn [4096][3072]
  bf16* Vtw = (bf16*)(ws + 83886080);         // 24 MiB: V-attn^T [32][192][2048]
  bf16* Im  = (bf16*)(ws + 109051904);        // 24 MiB: inter [4096][3072]

  cvt_x_kernel<<<4096, 256, 0, stream>>>(X, Xb);
  transpose_cvt_kernel<<<3072, 256, 0, stream>>>(q_w, Wqt, 1024, 3072);
  transpose_cvt_kernel<<<3072, 256, 0, stream>>>(v_w, Wvt, 1024, 3072);
  transpose_cvt_kernel<<<3072, 256, 0, stream>>>(k_w, Wkt, 1024, 3072);
  transpose_cvt_kernel<<<3072, 256, 0, stream>>>(o_w, Wot, 3072, 1024);

  // quirk: k_mat uses v_w/v_b, v_mat uses k_w/k_b
  gemm_bf16_kernel<0><<<768, 256, 0, stream>>>(Xb, Wqt, q_b, Qm, 4096, 3072, 1024);
  gemm_bf16_kernel<0><<<768, 256, 0, stream>>>(Xb, Wvt, v_b, Km, 4096, 3072, 1024);
  gemm_bf16_kernel<1><<<768, 256, 0, stream>>>(Xb, Wkt, k_b, Vtw, 4096, 3072, 1024);

  attn_kernel<<<256, 512, 0, stream>>>(Qm, Km, Vtw, Im);

  gemm_bf16_kernel<2><<<256, 256, 0, stream>>>(Im, Wot, o_b, d_out, 4096, 1024, 3072);
}